// Round 4
// baseline (512.607 us; speedup 1.0000x reference)
//
#include <hip/hip_runtime.h>
#include <math.h>
#include <float.h>
#include <limits.h>

#define N 8192
#define D 64
#define TOPK 32
#define TILE 128
#define CAP 1024

// orderable-uint encoding of float: a > b  <=>  ford(a) > ford(b)
__device__ __forceinline__ unsigned ford(float f) {
    unsigned u = __float_as_uint(f);
    return u ^ ((u & 0x80000000u) ? 0xFFFFFFFFu : 0x80000000u);
}
__device__ __forceinline__ float finv(unsigned u) {
    unsigned b = (u & 0x80000000u) ? (u ^ 0x80000000u) : ~u;
    return __uint_as_float(b);
}

// ---------------------------------------------------------------------------
// Kernel 0: zero the dense N*N section of d_out (score section fully
// overwritten by topk). Pure-BW grid-stride float4 stores.
// ---------------------------------------------------------------------------
__global__ __launch_bounds__(256) void zero_kernel(float4* __restrict__ p)
{
    const int n4 = N * N / 4;
    const float4 zz = make_float4(0.f, 0.f, 0.f, 0.f);
    int stride = gridDim.x * 256;
    for (int i = blockIdx.x * 256 + threadIdx.x; i < n4; i += stride)
        p[i] = zz;
}

// ---------------------------------------------------------------------------
// Kernel 1: row norms of X1 and X2 -> nrm[0..2N)
// ---------------------------------------------------------------------------
__global__ __launch_bounds__(256) void norms_kernel(
    const float* __restrict__ X1, const float* __restrict__ X2,
    float* __restrict__ nrm)
{
    int id = blockIdx.x * blockDim.x + threadIdx.x;
    if (id >= 2 * N) return;
    const float* X = (id < N) ? X1 : X2;
    int r = (id < N) ? id : id - N;
    const float4* p = (const float4*)(X + (size_t)r * D);
    float s = 0.f;
#pragma unroll
    for (int q = 0; q < D / 4; ++q) {
        float4 v = p[q];
        s += v.x * v.x + v.y * v.y + v.z * v.z + v.w * v.w;
    }
    nrm[id] = s;
}

// ---------------------------------------------------------------------------
// Kernel 2: stores -max(sq,0) (monotone proxy for -sqrt; sqrt applied to the
// 32 winners in topk -> identical final values). Emits per-row 128-col tile
// maxes. 128x128 tile, 8x8/thread, XOR-swizzled LDS (conflict-free b128).
// ---------------------------------------------------------------------------
__global__ __launch_bounds__(256, 2) void dist_kernel(
    const float* __restrict__ X1, const float* __restrict__ X2,
    const float* __restrict__ nrm, float* __restrict__ dst,
    float* __restrict__ tmax, int have_tmax)
{
    __shared__ float As[D * TILE];
    __shared__ float Bs[D * TILE];

    const int t = threadIdx.x;
    const int row0 = blockIdx.y * TILE;
    const int col0 = blockIdx.x * TILE;

#pragma unroll
    for (int p = 0; p < 8; ++p) {
        int lin = p * 256 + t;
        int r   = lin >> 4;
        int d4  = (lin & 15) << 2;
        int g   = (d4 >> 2) & 7;
        int cb  = r ^ (g << 3);
        float4 a = *(const float4*)(X1 + (size_t)(row0 + r) * D + d4);
        As[(d4 + 0) * TILE + cb] = a.x;
        As[(d4 + 1) * TILE + cb] = a.y;
        As[(d4 + 2) * TILE + cb] = a.z;
        As[(d4 + 3) * TILE + cb] = a.w;
        float4 b = *(const float4*)(X2 + (size_t)(col0 + r) * D + d4);
        Bs[(d4 + 0) * TILE + cb] = b.x;
        Bs[(d4 + 1) * TILE + cb] = b.y;
        Bs[(d4 + 2) * TILE + cb] = b.z;
        Bs[(d4 + 3) * TILE + cb] = b.w;
    }
    __syncthreads();

    const int tx = t & 15;
    const int ty = t >> 4;
    float acc[8][8] = {};

#pragma unroll 8
    for (int k = 0; k < D; ++k) {
        int gk  = (k >> 2) & 7;
        int ab  = k * TILE + ((ty ^ gk) << 3);
        int bb0 = k * TILE + ((4 * tx) ^ (gk << 3));
        float4 a0 = *(const float4*)&As[ab];
        float4 a1 = *(const float4*)&As[ab + 4];
        float4 b0 = *(const float4*)&Bs[bb0];
        float4 b1 = *(const float4*)&Bs[bb0 + 64];
        float av[8] = {a0.x, a0.y, a0.z, a0.w, a1.x, a1.y, a1.z, a1.w};
        float bv[8] = {b0.x, b0.y, b0.z, b0.w, b1.x, b1.y, b1.z, b1.w};
#pragma unroll
        for (int i = 0; i < 8; ++i)
#pragma unroll
            for (int j = 0; j < 8; ++j)
                acc[i][j] += av[i] * bv[j];
    }

    float na[8], nb[8];
#pragma unroll
    for (int i = 0; i < 8; ++i) na[i] = nrm[row0 + 8 * ty + i];
#pragma unroll
    for (int q = 0; q < 4; ++q) {
        nb[q]     = nrm[N + col0 + 4 * tx + q];
        nb[4 + q] = nrm[N + col0 + 64 + 4 * tx + q];
    }

    float rmax[8];
#pragma unroll
    for (int i = 0; i < 8; ++i) rmax[i] = -FLT_MAX;

#pragma unroll
    for (int i = 0; i < 8; ++i) {
        float* po = dst + (size_t)(row0 + 8 * ty + i) * N + col0 + 4 * tx;
        float4 o0, o1;
        float* f0 = (float*)&o0;
        float* f1 = (float*)&o1;
#pragma unroll
        for (int q = 0; q < 4; ++q) {
            float s0 = na[i] + nb[q] - 2.0f * acc[i][q];
            f0[q] = -fmaxf(s0, 0.0f);
            float s1 = na[i] + nb[4 + q] - 2.0f * acc[i][4 + q];
            f1[q] = -fmaxf(s1, 0.0f);
            rmax[i] = fmaxf(rmax[i], fmaxf(f0[q], f1[q]));
        }
        *(float4*)po        = o0;
        *(float4*)(po + 64) = o1;
    }

    if (have_tmax) {
#pragma unroll
        for (int i = 0; i < 8; ++i) {
            float mv = rmax[i];
            mv = fmaxf(mv, __shfl_down(mv, 8, 16));
            mv = fmaxf(mv, __shfl_down(mv, 4, 16));
            mv = fmaxf(mv, __shfl_down(mv, 2, 16));
            mv = fmaxf(mv, __shfl_down(mv, 1, 16));
            if (tx == 0)
                tmax[(size_t)(row0 + 8 * ty + i) * 64 + blockIdx.x] = mv;
        }
    }
}

// ---------------------------------------------------------------------------
// Kernel 3: one wave per row. thr = 32nd-largest tile-max. fastmode: read
// ONLY tiles with max >= thr (>=32 tiles, covers all survivors incl. ties)
// from src (=ws matrix); out already zeroed -> scatter only. Fallback
// (!fastmode): src = out, read all tiles, self-zero + scatter (R3-proven).
// ---------------------------------------------------------------------------
__global__ __launch_bounds__(256) void topk_kernel(
    const float* __restrict__ src, float* __restrict__ out,
    float* __restrict__ score_out, const float* __restrict__ tmax,
    int have_tmax, int fastmode)
{
    __shared__ unsigned long long cand[4][CAP];   // 32 KB
    __shared__ int qlist[4][64];
    __shared__ int scnt[4];

    const int t    = threadIdx.x;
    const int w    = t >> 6;
    const int lane = t & 63;
    const int r    = blockIdx.x * 4 + w;
    const float*  rowsrc = src + (size_t)r * N;
    const float4* row4   = (const float4*)rowsrc;

    // ---- threshold ----
    float thr;
    if (have_tmax) {
        float tm = tmax[(size_t)r * 64 + lane];
        unsigned km = ford(tm);
        int rk = 0;
#pragma unroll
        for (int l = 0; l < 64; ++l) {
            unsigned o = __shfl(km, l);
            rk += (o > km || (o == km && l < lane)) ? 1 : 0;
        }
        unsigned long long bm = __ballot(rk == 31);
        thr = __shfl(tm, __ffsll((long long)bm) - 1);

        bool qual = fastmode ? (tm >= thr) : true;
        unsigned long long qm = __ballot(qual);
        int nqq = __popcll(qm);
        if (qual) {
            int pos = __popcll(qm & ((lane == 0) ? 0ull : (~0ull >> (64 - lane))));
            qlist[w][pos] = lane;
        }
        if (lane == 0) scnt[w] = 0;
        __builtin_amdgcn_s_waitcnt(0xC07F);   // lgkmcnt(0)

        // ---- compact survivors from qualifying tiles (2 tiles / pass) ----
        for (int m = 0; m < nqq; m += 2) {
            int slot = m + (lane >> 5);
            bool valid = slot < nqq;
            int tile = qlist[w][valid ? slot : m];
            float4 x = row4[tile * 32 + (lane & 31)];
            float vs[4] = {x.x, x.y, x.z, x.w};
#pragma unroll
            for (int q = 0; q < 4; ++q) {
                float v = vs[q];
                if (valid && v >= thr) {
                    int p = atomicAdd(&scnt[w], 1);
                    if (p < CAP) {
                        int j = tile * 128 + 4 * (lane & 31) + q;
                        cand[w][p] = ((unsigned long long)ford(v) << 32) |
                                     (unsigned)(8191 - j);
                    }
                }
            }
        }
        __builtin_amdgcn_s_waitcnt(0xC07F);
    } else {
        // no-ws fallback: thr = min of per-lane maxes over the full row
        float lm = -FLT_MAX;
#pragma unroll 8
        for (int c = 0; c < 32; ++c) {
            float4 x = row4[c * 64 + lane];
            lm = fmaxf(lm, fmaxf(fmaxf(x.x, x.y), fmaxf(x.z, x.w)));
        }
        thr = lm;
        for (int off = 32; off > 0; off >>= 1)
            thr = fminf(thr, __shfl_xor(thr, off));
        if (lane == 0) scnt[w] = 0;
        __builtin_amdgcn_s_waitcnt(0xC07F);
        for (int c = 0; c < 32; ++c) {
            float4 x = row4[c * 64 + lane];
            float vs[4] = {x.x, x.y, x.z, x.w};
#pragma unroll
            for (int q = 0; q < 4; ++q) {
                float v = vs[q];
                if (v >= thr) {
                    int p = atomicAdd(&scnt[w], 1);
                    if (p < CAP) {
                        int j = 4 * (c * 64 + lane) + q;
                        cand[w][p] = ((unsigned long long)ford(v) << 32) |
                                     (unsigned)(8191 - j);
                    }
                }
            }
        }
        __builtin_amdgcn_s_waitcnt(0xC07F);
    }
    const int n = min(scnt[w], CAP);

    // ---- 32 x wave argmax over packed keys (value desc, index asc) ----
    unsigned long long mykey = 0ull;
    for (int it = 0; it < TOPK; ++it) {
        unsigned long long b = 0ull; int bp = 0;
        for (int q = lane; q < n; q += 64) {
            unsigned long long kk = cand[w][q];
            if (kk > b) { b = kk; bp = q; }
        }
        for (int off = 32; off > 0; off >>= 1) {
            unsigned long long ob = __shfl_down(b, off);
            int op = __shfl_down(bp, off);
            if (ob > b) { b = ob; bp = op; }
        }
        unsigned long long b0 = __shfl(b, 0);
        int bp0 = __shfl(bp, 0);
        if (lane == it) { mykey = b0; cand[w][bp0] = 0ull; }
    }

    // ---- sqrt + softmax on the 32 winners (rank == lane) ----
    float myv = 0.f; int myj = 0;
    if (lane < TOPK) {
        float sv = finv((unsigned)(mykey >> 32));   // stored -max(sq,0)
        myv = -sqrtf(-sv);
        myj = 8191 - (int)(mykey & 0xFFFFFFFFu);
    }
    float Mx = __shfl(myv, 0);
    float e = (lane < TOPK) ? expf(myv - Mx) : 0.f;
    float Z = e;
    for (int off = 32; off > 0; off >>= 1) Z += __shfl_xor(Z, off);
    float s = e / Z;
    if (lane < TOPK) score_out[(size_t)r * TOPK + lane] = s;

    float* rowout = out + (size_t)r * N;
    if (!fastmode) {
        const float4 zz = make_float4(0.f, 0.f, 0.f, 0.f);
#pragma unroll 8
        for (int c = 0; c < 32; ++c) ((float4*)rowout)[c * 64 + lane] = zz;
        __builtin_amdgcn_s_waitcnt(0x0F70);   // vmcnt(0)
    }
    if (lane < TOPK) rowout[myj] = s;
}

// ---------------------------------------------------------------------------
extern "C" void kernel_launch(void* const* d_in, const int* in_sizes, int n_in,
                              void* d_out, int out_size, void* d_ws, size_t ws_size,
                              hipStream_t stream)
{
    const float* X1 = (const float*)d_in[0];
    const float* X2 = (const float*)d_in[1];
    float* out  = (float*)d_out;
    float* nrm  = (float*)d_ws;                 // 2N floats
    float* tmax = nrm + 2 * N;                  // N*64 floats
    float* dmat = tmax + (size_t)N * 64;        // N*N floats (256 MB)

    size_t need_tmax = (size_t)(2 * N + (size_t)N * 64) * sizeof(float);
    size_t need_full = need_tmax + (size_t)N * N * sizeof(float);
    int have_tmax = (ws_size >= need_tmax) ? 1 : 0;
    int fastmode  = (ws_size >= need_full) ? 1 : 0;

    float* dst = fastmode ? dmat : out;

    norms_kernel<<<(2 * N + 255) / 256, 256, 0, stream>>>(X1, X2, nrm);

    dim3 grid(N / TILE, N / TILE);
    dist_kernel<<<grid, 256, 0, stream>>>(X1, X2, nrm, dst, tmax, have_tmax);

    if (fastmode)
        zero_kernel<<<4096, 256, 0, stream>>>((float4*)out);

    topk_kernel<<<N / 4, 256, 0, stream>>>(dst, out, out + (size_t)N * N,
                                           tmax, have_tmax, fastmode);
}